// Round 6
// baseline (51.612 us; speedup 1.0000x reference)
//
#include <hip/hip_runtime.h>
#include <hip/hip_bf16.h>

// Problem constants (KANLayer): B=8192, I=256, O=256, NUM_BASIS=7, ORDER=3
#define B_SZ 8192
#define I_SZ 256
#define O_SZ 256
#define KDIM 2048  // I_SZ * 8  (7 basis + 1 silu per input feature)
#define BM 32      // rows per block
#define BN 128     // output cols per block
#define BKT 64     // K per tile = 8 features
#define NT 32      // KDIM / BKT

typedef __bf16 bf16x8 __attribute__((ext_vector_type(8)));
typedef float f32x4 __attribute__((ext_vector_type(4)));

// ---- monotone uint <-> float for order-independent atomic min/max ----
__device__ __forceinline__ unsigned fkey(float f) {
  unsigned u = __float_as_uint(f);
  return (u & 0x80000000u) ? ~u : (u | 0x80000000u);
}
__device__ __forceinline__ float funkey(unsigned k) {
  unsigned u = (k & 0x80000000u) ? (k ^ 0x80000000u) : ~k;
  return __uint_as_float(u);
}

// Kernel 1: per-column min/max (proven round-2 shape). 128 blocks x 256 thr;
// block covers 64 rows via float4 (ILP), LDS-reduce, 64 threads do atomics.
__global__ __launch_bounds__(256) void minmax_partial(
    const float* __restrict__ x, unsigned* __restrict__ smin,
    unsigned* __restrict__ smax) {
  const int cg = threadIdx.x & 63;  // column group (4 cols via float4)
  const int rs = threadIdx.x >> 6;  // row subgroup 0..3
  const int r0 = blockIdx.x * 64;
  const float* p = x + (size_t)(r0 + rs) * I_SZ + cg * 4;
  float4 mn = {1e30f, 1e30f, 1e30f, 1e30f};
  float4 mx = {-1e30f, -1e30f, -1e30f, -1e30f};
#pragma unroll
  for (int k = 0; k < 16; ++k) {
    const float4 v = *reinterpret_cast<const float4*>(p + (size_t)k * 4 * I_SZ);
    mn.x = fminf(mn.x, v.x); mn.y = fminf(mn.y, v.y);
    mn.z = fminf(mn.z, v.z); mn.w = fminf(mn.w, v.w);
    mx.x = fmaxf(mx.x, v.x); mx.y = fmaxf(mx.y, v.y);
    mx.z = fmaxf(mx.z, v.z); mx.w = fmaxf(mx.w, v.w);
  }
  __shared__ float rmn[4][I_SZ], rmx[4][I_SZ];
  *reinterpret_cast<float4*>(&rmn[rs][cg * 4]) = mn;
  *reinterpret_cast<float4*>(&rmx[rs][cg * 4]) = mx;
  __syncthreads();
  if (threadIdx.x < 64) {
#pragma unroll
    for (int c = 0; c < 4; ++c) {
      const int col = threadIdx.x * 4 + c;
      const float a = fminf(fminf(rmn[0][col], rmn[1][col]),
                            fminf(rmn[2][col], rmn[3][col]));
      const float b = fmaxf(fmaxf(rmx[0][col], rmx[1][col]),
                            fmaxf(rmx[2][col], rmx[3][col]));
      atomicMin(&smin[col], fkey(a));
      atomicMax(&smax[col], fkey(b));
    }
  }
}

// Kernel 2: pack weights -> Wp[o, i*8+m] bf16, pre-swizzled (unit ^= o&7).
__global__ void pack_W(const float* __restrict__ bw,
                       const float* __restrict__ sw,
                       const float* __restrict__ coeff,
                       __hip_bfloat16* __restrict__ W) {
  const int idx = blockIdx.x * blockDim.x + threadIdx.x;  // 0..O*I-1
  const int i = idx & (I_SZ - 1);
  const int o = idx >> 8;
  const float s = sw[idx];
  union { __hip_bfloat16 h[8]; float4 f4; } u;
#pragma unroll
  for (int m = 0; m < 7; ++m)
    u.h[m] = __float2bfloat16(coeff[(size_t)idx * 7 + m] * s);
  u.h[7] = __float2bfloat16(bw[idx]);
  const size_t off = (size_t)o * KDIM + (size_t)((i ^ (o & 7)) << 3);
  *reinterpret_cast<float4*>(&W[off]) = u.f4;
}

// ---- async global->LDS 16B copy ----
__device__ __forceinline__ void async16(const __hip_bfloat16* g, __hip_bfloat16* l) {
  __builtin_amdgcn_global_load_lds(
      (const __attribute__((address_space(1))) void*)g,
      (__attribute__((address_space(3))) void*)l, 16, 0, 0);
}

// Kernel 3: fused basis-build + GEMM.
// Basis via closed-form uniform cubic B-spline (== reference's truncated
// de Boor: standard values for xn<0.4, zero for xn>0.4, cell-6/u=1 at 0.4).
// Block = 32 rows x 128 cols, 256 threads (4 waves), grid 512 = 2 blocks/CU.
// B double-buffered (global_load_lds, counted vmcnt), A double-buffered,
// one s_barrier per K-step. Per-column scales derived in-prologue.
__global__ __launch_bounds__(256, 2) void gemm_fused(
    const float* __restrict__ x, const __hip_bfloat16* __restrict__ W,
    const unsigned* __restrict__ smin, const unsigned* __restrict__ smax,
    const float* __restrict__ bias, float* __restrict__ out) {
  __shared__ __align__(16) __hip_bfloat16 Alds[2][BM * BKT];   // 2 x 4KB
  __shared__ __align__(16) __hip_bfloat16 Blds[2][BN * BKT];   // 2 x 16KB
  __shared__ float2 scl[I_SZ];                                  // 2KB

  const int t = threadIdx.x;
  const int lane = t & 63;
  const int wave = t >> 6;            // 0..3 -> n-offset 32*wave
  const int fr = lane & 15, fk = lane >> 4;

  // XCD-aware bijective swizzle (512 blocks, %8==0)
  const int bid = blockIdx.x;
  const int swz = (bid & 7) * 64 + (bid >> 3);
  const int bm = swz >> 1, bn = swz & 1;
  const int r0 = bm * BM;    // batch-row base
  const int c0 = bn * BN;    // output-col base

  // per-column scale: xn = fma(x, rhw, -centre*rhw)
  {
    const float mn = funkey(smin[t]);
    const float mx = funkey(smax[t]);
    const float w = fmaxf(mx - mn, 0.01f);
    const float rhw = 2.0f / w;
    scl[t] = make_float2(rhw, -0.5f * (mx + mn) * rhw);
  }

  // A-build mapping: thread -> (row, feature-within-tile); one eval/thread
  const int arow = t >> 3;   // 0..31
  const int af_  = t & 7;    // 0..7
  const float* xp = x + (size_t)(r0 + arow) * I_SZ + af_;

  const __hip_bfloat16* gb0 = W + (size_t)(c0 + (t >> 3)) * KDIM + (t & 7) * 8;

  f32x4 acc[2][2] = {{{0.f,0.f,0.f,0.f},{0.f,0.f,0.f,0.f}},
                     {{0.f,0.f,0.f,0.f},{0.f,0.f,0.f,0.f}}};

  auto stageB = [&](int buf, int kt) {
    const size_t k0 = (size_t)kt * BKT;
    async16(gb0 + k0,                      &Blds[buf][t * 8]);
    async16(gb0 + k0 + (size_t)32 * KDIM,  &Blds[buf][2048 + t * 8]);
    async16(gb0 + k0 + (size_t)64 * KDIM,  &Blds[buf][4096 + t * 8]);
    async16(gb0 + k0 + (size_t)96 * KDIM,  &Blds[buf][6144 + t * 8]);
  };

  // closed-form cubic B-spline: cell c = floor((xn+1)*5), u = frac;
  // nonzero slots j = c-3..c get {q0..q3}; all x 1/6; zero for s>7.
  auto buildA = [&](int buf, int kt, float xv) {
    const float2 s2 = scl[kt * 8 + af_];
    const float xn = __builtin_fmaf(xv, s2.x, s2.y);   // in [-1,1]
    const float sp = __builtin_fmaf(xn, 5.0f, 5.0f);   // in [0,10]
    const float cf = floorf(sp);
    const float c6 = fminf(cf, 6.0f);
    const int ci = (int)c6;
    const float u = sp - c6;                            // ==1 at sp==7
    const float zm = (sp > 7.0f) ? 0.0f : (1.0f / 6.0f);  // dead-mask + /6
    const float u2 = u * u;
    const float u3 = u2 * u;
    const float t1 = 1.0f - u;
    const float q3 = u3 * zm;
    const float q0 = (t1 * t1) * (t1 * zm);
    float h2 = __builtin_fmaf(-3.0f, u, 3.0f);          // -3u+3
    h2 = __builtin_fmaf(h2, u, 3.0f);
    h2 = __builtin_fmaf(h2, u, 1.0f);                   // -3u^3+3u^2+3u+1
    const float q2 = h2 * zm;
    float h1 = __builtin_fmaf(3.0f, u, -6.0f);          // 3u-6
    h1 = __builtin_fmaf(h1, u2, 4.0f);                  // 3u^3-6u^2+4
    const float q1 = h1 * zm;
    const float silu = xn * __builtin_amdgcn_rcpf(1.0f + __expf(-xn));
    union { __hip_bfloat16 h[8]; float4 f4; } uu;
#pragma unroll
    for (int j = 0; j < 7; ++j) {
      float v = 0.0f;
      v = (ci == j + 3) ? q0 : v;
      v = (ci == j + 2) ? q1 : v;
      v = (ci == j + 1) ? q2 : v;
      v = (ci == j)     ? q3 : v;
      uu.h[j] = __float2bfloat16(v);
    }
    uu.h[7] = __float2bfloat16(silu);
    const int unit = af_ ^ (arow & 7);
    *reinterpret_cast<float4*>(&Alds[buf][arow * BKT + unit * 8]) = uu.f4;
  };

  auto compute = [&](int bbuf, int abuf) {
    bf16x8 af[2][2], bg[2][2];
#pragma unroll
    for (int m = 0; m < 2; ++m)
#pragma unroll
      for (int kk = 0; kk < 2; ++kk) {
        const int row = m * 16 + fr;
        const int unit = ((kk << 2) | fk) ^ (row & 7);
        af[m][kk] = *reinterpret_cast<const bf16x8*>(&Alds[abuf][row * BKT + unit * 8]);
      }
#pragma unroll
    for (int n = 0; n < 2; ++n)
#pragma unroll
      for (int kk = 0; kk < 2; ++kk) {
        const int row = wave * 32 + n * 16 + fr;
        const int unit = ((kk << 2) | fk) ^ (row & 7);
        bg[n][kk] = *reinterpret_cast<const bf16x8*>(&Blds[bbuf][row * BKT + unit * 8]);
      }
#pragma unroll
    for (int kk = 0; kk < 2; ++kk)
#pragma unroll
      for (int m = 0; m < 2; ++m)
#pragma unroll
        for (int n = 0; n < 2; ++n)
          acc[m][n] = __builtin_amdgcn_mfma_f32_16x16x32_bf16(
              af[m][kk], bg[n][kk], acc[m][n], 0, 0, 0);
  };

  // prologue
  const float xv0 = xp[0];
  __syncthreads();              // scl visible (full drain, once)
  stageB(0, 0);
  float xpf = xp[8];            // x for tile 1 (issued after stage)
  buildA(0, 0, xv0);
  asm volatile("s_waitcnt vmcnt(1) lgkmcnt(0)" ::: "memory");  // B0+A0 ready
  __builtin_amdgcn_s_barrier();
  asm volatile("" ::: "memory");

  for (int kt = 0; kt < NT - 1; ++kt) {
    const int cb = kt & 1, nb = cb ^ 1;
    stageB(nb, kt + 1);                      // 4 async16
    const float xpf2 = xp[min(kt + 2, NT - 1) * 8];  // 1 load, clamped
    buildA(nb, kt + 1, xpf);
    xpf = xpf2;
    compute(cb, cb);
    // stage(kt+1) drained (only the x load may stay in flight) + LDS done
    asm volatile("s_waitcnt vmcnt(1) lgkmcnt(0)" ::: "memory");
    __builtin_amdgcn_s_barrier();
    asm volatile("" ::: "memory");
  }
  compute((NT - 1) & 1, (NT - 1) & 1);

  // epilogue: C/D layout col=lane&15, row=(lane>>4)*4+reg  [m89/m91]
#pragma unroll
  for (int m = 0; m < 2; ++m)
#pragma unroll
    for (int n = 0; n < 2; ++n) {
      const int col = c0 + wave * 32 + n * 16 + fr;
      const float bc = bias[col];
#pragma unroll
      for (int r = 0; r < 4; ++r) {
        const int row = r0 + m * 16 + fk * 4 + r;
        out[(size_t)row * O_SZ + col] = acc[m][n][r] + bc;
      }
    }
}

extern "C" void kernel_launch(void* const* d_in, const int* in_sizes, int n_in,
                              void* d_out, int out_size, void* d_ws, size_t ws_size,
                              hipStream_t stream) {
  const float* x     = (const float*)d_in[0];
  const float* bw    = (const float*)d_in[1];
  const float* sw    = (const float*)d_in[2];
  const float* coeff = (const float*)d_in[3];
  const float* bias  = (const float*)d_in[4];
  float* out = (float*)d_out;

  char* ws = (char*)d_ws;
  __hip_bfloat16* Wbuf = (__hip_bfloat16*)ws;                    // 1 MiB
  unsigned* smin = (unsigned*)(ws + (size_t)O_SZ * KDIM * 2);
  unsigned* smax = smin + I_SZ;

  hipMemsetAsync(smin, 0xFF, I_SZ * sizeof(unsigned), stream);  // key(min) id
  hipMemsetAsync(smax, 0x00, I_SZ * sizeof(unsigned), stream);  // key(max) id

  minmax_partial<<<128, 256, 0, stream>>>(x, smin, smax);
  pack_W<<<(O_SZ * I_SZ) / 256, 256, 0, stream>>>(bw, sw, coeff, Wbuf);
  gemm_fused<<<(B_SZ / BM) * (O_SZ / BN), 256, 0, stream>>>(x, Wbuf, smin,
                                                            smax, bias, out);
}

// Round 7
// 42.311 us; speedup vs baseline: 1.2198x; 1.2198x over previous
//
#include <hip/hip_runtime.h>
#include <hip/hip_bf16.h>

// Problem constants (KANLayer): B=8192, I=256, O=256, NUM_BASIS=7, ORDER=3
#define B_SZ 8192
#define I_SZ 256
#define O_SZ 256
#define KDIM 2048  // I_SZ * 8  (7 basis + 1 silu per input feature)
#define BM 32      // rows per block
#define BN 128     // output cols per block
#define BKT 64     // K per tile = 8 features
#define NT 32      // KDIM / BKT
#define NPART 128  // min/max partial rows

typedef __bf16 bf16x8 __attribute__((ext_vector_type(8)));
typedef float f32x4 __attribute__((ext_vector_type(4)));

// Kernel 1: per-column min/max partials. 128 blocks x 256 threads; block
// handles 64 rows via float4 loads (ILP), LDS-reduce over 4 row-subgroups,
// plain stores of one partial row per block (no atomics, no memset needed).
__global__ __launch_bounds__(256) void minmax_partial(
    const float* __restrict__ x, float* __restrict__ pmin,
    float* __restrict__ pmax) {
  const int cg = threadIdx.x & 63;  // column group (4 cols via float4)
  const int rs = threadIdx.x >> 6;  // row subgroup 0..3
  const int r0 = blockIdx.x * 64;
  const float* p = x + (size_t)(r0 + rs) * I_SZ + cg * 4;
  float4 mn = {1e30f, 1e30f, 1e30f, 1e30f};
  float4 mx = {-1e30f, -1e30f, -1e30f, -1e30f};
#pragma unroll
  for (int k = 0; k < 16; ++k) {
    const float4 v = *reinterpret_cast<const float4*>(p + (size_t)k * 4 * I_SZ);
    mn.x = fminf(mn.x, v.x); mn.y = fminf(mn.y, v.y);
    mn.z = fminf(mn.z, v.z); mn.w = fminf(mn.w, v.w);
    mx.x = fmaxf(mx.x, v.x); mx.y = fmaxf(mx.y, v.y);
    mx.z = fmaxf(mx.z, v.z); mx.w = fmaxf(mx.w, v.w);
  }
  __shared__ float rmn[4][I_SZ], rmx[4][I_SZ];
  *reinterpret_cast<float4*>(&rmn[rs][cg * 4]) = mn;
  *reinterpret_cast<float4*>(&rmx[rs][cg * 4]) = mx;
  __syncthreads();
  if (threadIdx.x < 64) {
    float4 a, b;
    const int c0 = threadIdx.x * 4;
    a.x = fminf(fminf(rmn[0][c0+0], rmn[1][c0+0]), fminf(rmn[2][c0+0], rmn[3][c0+0]));
    a.y = fminf(fminf(rmn[0][c0+1], rmn[1][c0+1]), fminf(rmn[2][c0+1], rmn[3][c0+1]));
    a.z = fminf(fminf(rmn[0][c0+2], rmn[1][c0+2]), fminf(rmn[2][c0+2], rmn[3][c0+2]));
    a.w = fminf(fminf(rmn[0][c0+3], rmn[1][c0+3]), fminf(rmn[2][c0+3], rmn[3][c0+3]));
    b.x = fmaxf(fmaxf(rmx[0][c0+0], rmx[1][c0+0]), fmaxf(rmx[2][c0+0], rmx[3][c0+0]));
    b.y = fmaxf(fmaxf(rmx[0][c0+1], rmx[1][c0+1]), fmaxf(rmx[2][c0+1], rmx[3][c0+1]));
    b.z = fmaxf(fmaxf(rmx[0][c0+2], rmx[1][c0+2]), fmaxf(rmx[2][c0+2], rmx[3][c0+2]));
    b.w = fmaxf(fmaxf(rmx[0][c0+3], rmx[1][c0+3]), fmaxf(rmx[2][c0+3], rmx[3][c0+3]));
    *reinterpret_cast<float4*>(&pmin[blockIdx.x * I_SZ + c0]) = a;
    *reinterpret_cast<float4*>(&pmax[blockIdx.x * I_SZ + c0]) = b;
  }
}

// Kernel 2: pack weights -> Wp[o, i*8+m] bf16, pre-swizzled (unit ^= o&7),
// PLUS (block 0) reduce the min/max partials into per-column scale pair
// (rhw, -centre*rhw) so the GEMM computes xn via one fma.
__global__ void pack_W(const float* __restrict__ bw,
                       const float* __restrict__ sw,
                       const float* __restrict__ coeff,
                       __hip_bfloat16* __restrict__ W,
                       const float* __restrict__ pmin,
                       const float* __restrict__ pmax,
                       float* __restrict__ cenrhw) {
  const int idx = blockIdx.x * blockDim.x + threadIdx.x;  // 0..O*I-1
  const int i = idx & (I_SZ - 1);
  const int o = idx >> 8;
  const float s = sw[idx];
  union { __hip_bfloat16 h[8]; float4 f4; } u;
#pragma unroll
  for (int m = 0; m < 7; ++m)
    u.h[m] = __float2bfloat16(coeff[(size_t)idx * 7 + m] * s);
  u.h[7] = __float2bfloat16(bw[idx]);
  const size_t off = (size_t)o * KDIM + (size_t)((i ^ (o & 7)) << 3);
  *reinterpret_cast<float4*>(&W[off]) = u.f4;

  if (blockIdx.x == 0) {
    const int c = threadIdx.x;
    float mn = 1e30f, mx = -1e30f;
#pragma unroll 8
    for (int p = 0; p < NPART; ++p) {
      mn = fminf(mn, pmin[p * I_SZ + c]);
      mx = fmaxf(mx, pmax[p * I_SZ + c]);
    }
    const float width = fmaxf(mx - mn, 0.01f);
    const float rhw = 2.0f / width;
    cenrhw[2 * c]     = rhw;
    cenrhw[2 * c + 1] = -0.5f * (mx + mn) * rhw;
  }
}

// ---- async global->LDS 16B copy ----
__device__ __forceinline__ void async16(const __hip_bfloat16* g, __hip_bfloat16* l) {
  __builtin_amdgcn_global_load_lds(
      (const __attribute__((address_space(1))) void*)g,
      (__attribute__((address_space(3))) void*)l, 16, 0, 0);
}

// Kernel 3: fused basis-build + GEMM (round-4 structure, cheap basis).
// Basis via closed-form uniform cubic B-spline (== reference's truncated
// de Boor: standard values for xn<0.4, zero for xn>0.4, cell-6/u=1 at 0.4).
// Block = 32 rows x 128 cols, 256 threads (4 waves), grid 512 = 2 blocks/CU.
// Plain __syncthreads double-buffered loop (compiler schedules waitcnts).
__global__ __launch_bounds__(256, 2) void gemm_fused(
    const float* __restrict__ x, const __hip_bfloat16* __restrict__ W,
    const float* __restrict__ cenrhw, const float* __restrict__ bias,
    float* __restrict__ out) {
  __shared__ __align__(16) __hip_bfloat16 Alds[2][BM * BKT];   // 2 x 4KB
  __shared__ __align__(16) __hip_bfloat16 Blds[2][BN * BKT];   // 2 x 16KB
  __shared__ float2 scl[I_SZ];                                  // 2KB

  const int t = threadIdx.x;
  const int lane = t & 63;
  const int wave = t >> 6;            // 0..3 -> n-offset 32*wave
  const int fr = lane & 15, fk = lane >> 4;

  // XCD-aware bijective swizzle (512 blocks, %8==0)
  const int bid = blockIdx.x;
  const int swz = (bid & 7) * 64 + (bid >> 3);
  const int bm = swz >> 1, bn = swz & 1;
  const int r0 = bm * BM;    // batch-row base
  const int c0 = bn * BN;    // output-col base

  scl[t] = reinterpret_cast<const float2*>(cenrhw)[t];

  // A-build mapping: thread -> (row, feature-within-tile); one eval/thread
  const int arow = t >> 3;   // 0..31
  const int af_  = t & 7;    // 0..7
  const float* xp = x + (size_t)(r0 + arow) * I_SZ + af_;

  const __hip_bfloat16* gb0 = W + (size_t)(c0 + (t >> 3)) * KDIM + (t & 7) * 8;

  f32x4 acc[2][2] = {{{0.f,0.f,0.f,0.f},{0.f,0.f,0.f,0.f}},
                     {{0.f,0.f,0.f,0.f},{0.f,0.f,0.f,0.f}}};

  auto stageB = [&](int buf, int kt) {
    const size_t k0 = (size_t)kt * BKT;
    async16(gb0 + k0,                      &Blds[buf][t * 8]);
    async16(gb0 + k0 + (size_t)32 * KDIM,  &Blds[buf][2048 + t * 8]);
    async16(gb0 + k0 + (size_t)64 * KDIM,  &Blds[buf][4096 + t * 8]);
    async16(gb0 + k0 + (size_t)96 * KDIM,  &Blds[buf][6144 + t * 8]);
  };

  // closed-form cubic B-spline: cell c = floor((xn+1)*5), u = frac;
  // nonzero slots j = c-3..c get {q0..q3}; all x 1/6; zero for sp>7.
  auto buildA = [&](int buf, int kt, float xv) {
    const float2 s2 = scl[kt * 8 + af_];
    const float xn = __builtin_fmaf(xv, s2.x, s2.y);   // in [-1,1]
    const float sp = __builtin_fmaf(xn, 5.0f, 5.0f);   // in [0,10]
    const float cf = floorf(sp);
    const float c6 = fminf(cf, 6.0f);
    const int ci = (int)c6;
    const float u = sp - c6;                            // ==1 at sp==7
    const float zm = (sp > 7.0f) ? 0.0f : (1.0f / 6.0f);  // dead-mask + /6
    const float u2 = u * u;
    const float u3 = u2 * u;
    const float t1 = 1.0f - u;
    const float q3 = u3 * zm;
    const float q0 = (t1 * t1) * (t1 * zm);
    float h2 = __builtin_fmaf(-3.0f, u, 3.0f);          // -3u+3
    h2 = __builtin_fmaf(h2, u, 3.0f);
    h2 = __builtin_fmaf(h2, u, 1.0f);                   // -3u^3+3u^2+3u+1
    const float q2 = h2 * zm;
    float h1 = __builtin_fmaf(3.0f, u, -6.0f);          // 3u-6
    h1 = __builtin_fmaf(h1, u2, 4.0f);                  // 3u^3-6u^2+4
    const float q1 = h1 * zm;
    const float silu = xn * __builtin_amdgcn_rcpf(1.0f + __expf(-xn));
    union { __hip_bfloat16 h[8]; float4 f4; } uu;
#pragma unroll
    for (int j = 0; j < 7; ++j) {
      float v = 0.0f;
      v = (ci == j + 3) ? q0 : v;
      v = (ci == j + 2) ? q1 : v;
      v = (ci == j + 1) ? q2 : v;
      v = (ci == j)     ? q3 : v;
      uu.h[j] = __float2bfloat16(v);
    }
    uu.h[7] = __float2bfloat16(silu);
    const int unit = af_ ^ (arow & 7);
    *reinterpret_cast<float4*>(&Alds[buf][arow * BKT + unit * 8]) = uu.f4;
  };

  auto compute = [&](int buf) {
    bf16x8 af[2][2], bg[2][2];
#pragma unroll
    for (int m = 0; m < 2; ++m)
#pragma unroll
      for (int kk = 0; kk < 2; ++kk) {
        const int row = m * 16 + fr;
        const int unit = ((kk << 2) | fk) ^ (row & 7);
        af[m][kk] = *reinterpret_cast<const bf16x8*>(&Alds[buf][row * BKT + unit * 8]);
      }
#pragma unroll
    for (int n = 0; n < 2; ++n)
#pragma unroll
      for (int kk = 0; kk < 2; ++kk) {
        const int row = wave * 32 + n * 16 + fr;
        const int unit = ((kk << 2) | fk) ^ (row & 7);
        bg[n][kk] = *reinterpret_cast<const bf16x8*>(&Blds[buf][row * BKT + unit * 8]);
      }
#pragma unroll
    for (int kk = 0; kk < 2; ++kk)
#pragma unroll
      for (int m = 0; m < 2; ++m)
#pragma unroll
        for (int n = 0; n < 2; ++n)
          acc[m][n] = __builtin_amdgcn_mfma_f32_16x16x32_bf16(
              af[m][kk], bg[n][kk], acc[m][n], 0, 0, 0);
  };

  // prologue: x for tiles 0,1 loaded early; B tile 0 staged.
  const float xv0 = xp[0];
  float xpf = xp[8];            // tile 1
  __syncthreads();              // scl visible
  stageB(0, 0);
  buildA(0, 0, xv0);
  __syncthreads();              // A written + B staged
  int cur = 0;
  for (int kt = 0; kt < NT - 1; ++kt) {
    stageB(cur ^ 1, kt + 1);
    const float xpf2 = xp[min(kt + 2, NT - 1) * 8];  // issue early, clamped
    buildA(cur ^ 1, kt + 1, xpf);   // consumes value prefetched last iter
    compute(cur);
    __syncthreads();
    xpf = xpf2;
    cur ^= 1;
  }
  compute(cur);

  // epilogue: C/D layout col=lane&15, row=(lane>>4)*4+reg  [m89/m91]
#pragma unroll
  for (int m = 0; m < 2; ++m)
#pragma unroll
    for (int n = 0; n < 2; ++n) {
      const int col = c0 + wave * 32 + n * 16 + fr;
      const float bc = bias[col];
#pragma unroll
      for (int r = 0; r < 4; ++r) {
        const int row = r0 + m * 16 + fk * 4 + r;
        out[(size_t)row * O_SZ + col] = acc[m][n][r] + bc;
      }
    }
}

extern "C" void kernel_launch(void* const* d_in, const int* in_sizes, int n_in,
                              void* d_out, int out_size, void* d_ws, size_t ws_size,
                              hipStream_t stream) {
  const float* x     = (const float*)d_in[0];
  const float* bw    = (const float*)d_in[1];
  const float* sw    = (const float*)d_in[2];
  const float* coeff = (const float*)d_in[3];
  const float* bias  = (const float*)d_in[4];
  float* out = (float*)d_out;

  char* ws = (char*)d_ws;
  __hip_bfloat16* Wbuf = (__hip_bfloat16*)ws;                    // 1 MiB
  float* pmin   = (float*)(ws + (size_t)O_SZ * KDIM * 2);        // 128 KiB
  float* pmax   = pmin + NPART * I_SZ;                           // 128 KiB
  float* cenrhw = pmax + NPART * I_SZ;                           // 2 KiB

  minmax_partial<<<NPART, 256, 0, stream>>>(x, pmin, pmax);
  pack_W<<<(O_SZ * I_SZ) / 256, 256, 0, stream>>>(bw, sw, coeff, Wbuf,
                                                  pmin, pmax, cenrhw);
  gemm_fused<<<(B_SZ / BM) * (O_SZ / BN), 256, 0, stream>>>(x, Wbuf, cenrhw,
                                                            bias, out);
}